// Round 1
// baseline (1362.286 us; speedup 1.0000x reference)
//
#include <hip/hip_runtime.h>
#include <cstdint>
#include <cstddef>

typedef __bf16 bf16_t;
typedef __bf16 bf16x8 __attribute__((ext_vector_type(8)));
typedef float floatx4 __attribute__((ext_vector_type(4)));

// ---------------- helpers ----------------
__device__ __forceinline__ float wred_sum(float v) {
#pragma unroll
  for (int off = 32; off > 0; off >>= 1) v += __shfl_xor(v, off);
  return v;
}
__device__ __forceinline__ float wred_max(float v) {
#pragma unroll
  for (int off = 32; off > 0; off >>= 1) v = fmaxf(v, __shfl_xor(v, off));
  return v;
}
__device__ __forceinline__ void async16(const void* g, void* l) {
  __builtin_amdgcn_global_load_lds((const __attribute__((address_space(1))) void*)g,
                                   (__attribute__((address_space(3))) void*)l, 16, 0, 0);
}

// ---------------- generic batched bf16 GEMM ----------------
// C[M x N] = A[M x K] (row-major, lda) * B[N x K] (row-major = B^T, ldb)
// batch z decomposed z1 = z % nb1, z2 = z / nb1 with per-matrix strides.
// OUT_BF16: C is bf16, else fp32. RESID: C += Res (fp32, same indexing as C).
template <bool OUT_BF16, bool RESID>
__global__ __launch_bounds__(256) void st_gemm(
    const bf16_t* __restrict__ A, const bf16_t* __restrict__ B, void* Cp,
    const float* Res, int M, int N, int K, int lda, int ldb, int ldc, int nb1,
    long long sa1, long long sa2, long long sb1, long long sb2,
    long long sc1, long long sc2) {
  __shared__ bf16_t sA[128 * 32];
  __shared__ bf16_t sB[128 * 32];
  const int z = blockIdx.z;
  const int z1 = z % nb1, z2 = z / nb1;
  A += z1 * sa1 + z2 * sa2;
  B += z1 * sb1 + z2 * sb2;
  const long long coff = z1 * sc1 + z2 * sc2;
  const int tid = threadIdx.x;
  const int bm = blockIdx.x, bn = blockIdx.y;
  const int lane = tid & 63;
  const int wave = tid >> 6;
  const int wm = (wave >> 1) * 64, wn = (wave & 1) * 64;
  const int rowf = lane & 15, kq = (lane >> 4) * 8;

  floatx4 acc[4][4];
#pragma unroll
  for (int i = 0; i < 4; ++i)
#pragma unroll
    for (int j = 0; j < 4; ++j) acc[i][j] = floatx4{0.f, 0.f, 0.f, 0.f};

  for (int kt = 0; kt < K; kt += 32) {
#pragma unroll
    for (int it = 0; it < 2; ++it) {
      int slot = it * 256 + tid;
      int mi = slot >> 2, kc = slot & 3;
      int ar = bm * 128 + mi; if (ar > M - 1) ar = M - 1;
      int br = bn * 128 + mi; if (br > N - 1) br = N - 1;
      async16(A + (size_t)ar * lda + kt + kc * 8, (char*)sA + slot * 16);
      async16(B + (size_t)br * ldb + kt + kc * 8, (char*)sB + slot * 16);
    }
    __syncthreads();
    bf16x8 af[4], bv[4];
#pragma unroll
    for (int i = 0; i < 4; ++i) {
      af[i] = *(const bf16x8*)(sA + (wm + i * 16 + rowf) * 32 + kq);
      bv[i] = *(const bf16x8*)(sB + (wn + i * 16 + rowf) * 32 + kq);
    }
#pragma unroll
    for (int i = 0; i < 4; ++i)
#pragma unroll
      for (int j = 0; j < 4; ++j)
        acc[i][j] = __builtin_amdgcn_mfma_f32_16x16x32_bf16(af[i], bv[j], acc[i][j], 0, 0, 0);
    __syncthreads();
  }

  const int colBase = bn * 128 + wn + (lane & 15);
  const int rowBase = bm * 128 + wm + (lane >> 4) * 4;
#pragma unroll
  for (int i = 0; i < 4; ++i) {
#pragma unroll
    for (int j = 0; j < 4; ++j) {
      int col = colBase + j * 16;
      if (col >= N) continue;
#pragma unroll
      for (int r = 0; r < 4; ++r) {
        int row = rowBase + i * 16 + r;
        if (row >= M) continue;
        long long idx = coff + (long long)row * ldc + col;
        float v = acc[i][j][r];
        if (RESID) v += Res[idx];
        if (OUT_BF16) ((bf16_t*)Cp)[idx] = (bf16_t)v;
        else          ((float*)Cp)[idx] = v;
      }
    }
  }
}

// ---------------- tiled fp32 transpose (R x C) -> (C x R), batched ----------------
__global__ __launch_bounds__(256) void st_transpose2d(
    const float* __restrict__ in, float* __restrict__ out, int R, int Cc,
    long long inb, long long outb) {
  __shared__ float tile[32][33];
  const int ct = blockIdx.x, rt = blockIdx.y, b = blockIdx.z;
  in += (long long)b * inb;
  out += (long long)b * outb;
  const int tx = threadIdx.x & 31, ty = threadIdx.x >> 5;
#pragma unroll
  for (int k = 0; k < 4; ++k) {
    int r = rt * 32 + ty + k * 8;
    int c = ct * 32 + tx;
    tile[ty + k * 8][tx] = in[(size_t)r * Cc + c];
  }
  __syncthreads();
#pragma unroll
  for (int k = 0; k < 4; ++k) {
    int c = ct * 32 + ty + k * 8;
    int r = rt * 32 + tx;
    out[(size_t)c * R + r] = tile[tx][ty + k * 8];
  }
}

// ---------------- weight transpose fp32 (K x N) -> bf16 (N x Kpad), zero-padded ----------------
__global__ void st_wtrans(const float* __restrict__ src, bf16_t* __restrict__ dst,
                          int K, int Kpad, int N, int srcld, int coloff, long total) {
  long idx = (long)blockIdx.x * 256 + threadIdx.x;
  if (idx >= total) return;
  int kp = (int)(idx % Kpad);
  int n = (int)(idx / Kpad);
  float v = (kp < K) ? src[(size_t)kp * srcld + coloff + n] : 0.f;
  dst[idx] = (bf16_t)v;
}

// ---------------- CPB MLP tables ----------------
// tab[pos*8 + o] = mlp(rel(pos)); silu = x*sigmoid(x)
__global__ __launch_bounds__(256) void st_cpb(
    const float* __restrict__ w1, const float* __restrict__ b1,
    const float* __restrict__ w2, const float* __restrict__ b2,
    const float* __restrict__ w3, const float* __restrict__ b3,
    float* __restrict__ tab, int two_d) {
  const int pos = blockIdx.x, t = threadIdx.x;
  float r0, r1 = 0.f;
  if (two_d) { r0 = (float)(pos / 63 - 31); r1 = (float)(pos % 63 - 31); }
  else { r0 = (float)(pos - 7); }
  __shared__ float sh[256];
  float h = r0 * w1[t] + (two_d ? r1 * w1[256 + t] : 0.f) + b1[t];
  h = h / (1.f + expf(-h));
  sh[t] = h;
  __syncthreads();
  float h2 = b2[t];
  for (int j = 0; j < 256; ++j) h2 += sh[j] * w2[j * 256 + t];
  h2 = h2 / (1.f + expf(-h2));
  __syncthreads();
  sh[t] = h2;
  __syncthreads();
  if (t < 8) {
    float o = b3[t];
    for (int j = 0; j < 256; ++j) o += sh[j] * w3[j * 8 + t];
    tab[pos * 8 + t] = o;
  }
}

// ---------------- RMS norm (x / max(||x||,eps) * sqrt(512) * gamma) -> bf16 ----------------
__global__ __launch_bounds__(256) void st_rmsnorm(const float* __restrict__ x,
                                                  const float* __restrict__ gamma,
                                                  bf16_t* __restrict__ y) {
  const int token = blockIdx.x * 4 + (threadIdx.x >> 6);
  const int lane = threadIdx.x & 63;
  const float* xr = x + (size_t)token * 512;
  float v[8];
  float ss = 0.f;
#pragma unroll
  for (int k = 0; k < 8; ++k) { v[k] = xr[k * 64 + lane]; ss += v[k] * v[k]; }
  ss = wred_sum(ss);
  const float r = 22.627416998f / fmaxf(sqrtf(ss), 1e-12f);
  bf16_t* yr = y + (size_t)token * 512;
#pragma unroll
  for (int k = 0; k < 8; ++k) yr[k * 64 + lane] = (bf16_t)(v[k] * r * gamma[k * 64 + lane]);
}

__global__ void st_cast(const float* __restrict__ in, bf16_t* __restrict__ out, long n) {
  long i = (long)blockIdx.x * 256 + threadIdx.x;
  if (i < n) out[i] = (bf16_t)in[i];
}

// ---------------- V transpose: qkv -> vT[(bf*8+h)][d][j] ----------------
__global__ __launch_bounds__(256) void st_vtrans(const bf16_t* __restrict__ qkv,
                                                 bf16_t* __restrict__ vT) {
  __shared__ float tile[32][33];
  const int jt = blockIdx.x, dt = blockIdx.y, z = blockIdx.z;
  const int bf = z >> 3, h = z & 7;
  const int tx = threadIdx.x & 31, ty = threadIdx.x >> 5;
#pragma unroll
  for (int k = 0; k < 4; ++k) {
    int j = jt * 32 + ty + k * 8;
    int d = dt * 32 + tx;
    tile[ty + k * 8][tx] = (float)qkv[((size_t)(bf * 1024 + j)) * 1536 + 1024 + h * 64 + d];
  }
  __syncthreads();
#pragma unroll
  for (int k = 0; k < 4; ++k) {
    int d = dt * 32 + ty + k * 8;
    int j = jt * 32 + tx;
    vT[((size_t)z * 64 + d) * 1024 + j] = (bf16_t)tile[tx][ty + k * 8];
  }
}

// ---------------- spatial softmax with CPB bias: S fp32 -> P bf16 ----------------
__global__ __launch_bounds__(256) void st_softmax_sp(const float* __restrict__ S,
                                                     bf16_t* __restrict__ P,
                                                     const float* __restrict__ tab) {
  const int i = blockIdx.x;       // query row
  const int z = blockIdx.y;       // bf_local*8 + h
  const int h = z & 7;
  const int tid = threadIdx.x;
  const float* srow = S + ((size_t)z * 1024 + i) * 1024;
  bf16_t* prow = P + ((size_t)z * 1024 + i) * 1024;
  const int yi = i >> 5, xi = i & 31;
  float vals[4];
  float mx = -3.0e38f;
#pragma unroll
  for (int t = 0; t < 4; ++t) {
    int j = t * 256 + tid;
    int yj = j >> 5, xj = j & 31;
    int idx = (yi - yj + 31) * 63 + (xi - xj + 31);
    float v = srow[j] * 0.125f + tab[idx * 8 + h];
    vals[t] = v;
    mx = fmaxf(mx, v);
  }
  __shared__ float red[4];
  mx = wred_max(mx);
  if ((tid & 63) == 0) red[tid >> 6] = mx;
  __syncthreads();
  mx = fmaxf(fmaxf(red[0], red[1]), fmaxf(red[2], red[3]));
  float sum = 0.f;
#pragma unroll
  for (int t = 0; t < 4; ++t) { vals[t] = expf(vals[t] - mx); sum += vals[t]; }
  sum = wred_sum(sum);
  __syncthreads();  // protect red reuse
  if ((tid & 63) == 0) red[tid >> 6] = sum;
  __syncthreads();
  sum = red[0] + red[1] + red[2] + red[3];
  const float inv = 1.f / sum;
#pragma unroll
  for (int t = 0; t < 4; ++t) prow[t * 256 + tid] = (bf16_t)(vals[t] * inv);
}

// ---------------- temporal attention (seq=8), wave per (bhw, head) ----------------
__global__ __launch_bounds__(256) void st_tattn(const bf16_t* __restrict__ qkv,
                                                const float* __restrict__ tab,
                                                bf16_t* __restrict__ o) {
  const int wg = blockIdx.x * 4 + (threadIdx.x >> 6);
  const int bhw = wg >> 3, head = wg & 7;
  const int lane = threadIdx.x & 63;
  const size_t base = (size_t)bhw * 8 * 1536 + head * 64 + lane;
  float q[8], k[8], v[8];
#pragma unroll
  for (int f = 0; f < 8; ++f) {
    q[f] = (float)qkv[base + (size_t)f * 1536];
    k[f] = (float)qkv[base + (size_t)f * 1536 + 512];
    v[f] = (float)qkv[base + (size_t)f * 1536 + 1024];
  }
  float s[8][8];
#pragma unroll
  for (int i = 0; i < 8; ++i)
#pragma unroll
    for (int j = 0; j < 8; ++j) {
      float p = wred_sum(q[i] * k[j]);
      s[i][j] = p * 0.125f + tab[(i - j + 7) * 8 + head];
    }
#pragma unroll
  for (int i = 0; i < 8; ++i) {
    float mx = s[i][0];
#pragma unroll
    for (int j = 1; j < 8; ++j) mx = fmaxf(mx, s[i][j]);
    float sum = 0.f;
#pragma unroll
    for (int j = 0; j < 8; ++j) { s[i][j] = expf(s[i][j] - mx); sum += s[i][j]; }
    const float inv = 1.f / sum;
    float acc = 0.f;
#pragma unroll
    for (int j = 0; j < 8; ++j) acc += s[i][j] * inv * v[j];
    o[(size_t)(bhw * 8 + i) * 512 + head * 64 + lane] = (bf16_t)acc;
  }
}

// ---------------- permute (b,f,hw,c) <-> (b,hw,f,c) ----------------
__global__ void st_permute(const float* __restrict__ in, float* __restrict__ out, int dir) {
  size_t idx = (size_t)blockIdx.x * 256 + threadIdx.x;  // 8388608 total
  int c = (int)(idx & 511);
  size_t r = idx >> 9;
  size_t src;
  if (dir == 0) {  // out (b,hw,f,c) <- in (b,f,hw,c)
    int f = (int)(r & 7);
    int hw = (int)((r >> 3) & 1023);
    int b = (int)(r >> 13);
    src = ((((size_t)b * 8 + f) * 1024 + hw) << 9) + c;
  } else {         // out (b,f,hw,c) <- in (b,hw,f,c)
    int hw = (int)(r & 1023);
    int f = (int)((r >> 10) & 7);
    int b = (int)(r >> 13);
    src = ((((size_t)b * 1024 + hw) * 8 + f) << 9) + c;
  }
  out[idx] = in[src];
}

// ---------------- GeGLU + temporal shift + RMS -> yn bf16 (padded K=1376) ----------------
__global__ __launch_bounds__(256) void st_glu(const bf16_t* __restrict__ a,
                                              const bf16_t* __restrict__ g,
                                              const float* __restrict__ gamma,
                                              bf16_t* __restrict__ yn) {
  const int t = blockIdx.x;
  const int tid = threadIdx.x;
  const int f = (t >> 10) & 7;
  float y[6];
  float ss = 0.f;
#pragma unroll
  for (int kk = 0; kk < 6; ++kk) {
    int c = kk * 256 + tid;
    float yv = 0.f;
    if (c < 1365) {
      long src = t;
      bool valid = true;
      if (c >= 683) { if (f == 0) valid = false; else src = t - 1024; }
      if (valid) {
        float av = (float)a[src * 1365 + c];
        float gv = (float)g[src * 1365 + c];
        yv = av * 0.5f * gv * (1.f + erff(gv * 0.70710678f));
      }
    }
    y[kk] = yv;
    ss += yv * yv;
  }
  __shared__ float red[4];
  ss = wred_sum(ss);
  if ((tid & 63) == 0) red[tid >> 6] = ss;
  __syncthreads();
  ss = red[0] + red[1] + red[2] + red[3];
  const float r = sqrtf(1365.f) / fmaxf(sqrtf(ss), 1e-12f);
#pragma unroll
  for (int kk = 0; kk < 6; ++kk) {
    int c = kk * 256 + tid;
    if (c < 1365) yn[(size_t)t * 1376 + c] = (bf16_t)(y[kk] * r * gamma[c]);
  }
  if (tid < 11) yn[(size_t)t * 1376 + 1365 + tid] = (bf16_t)0.f;
}

// ---------------- launcher ----------------
extern "C" void kernel_launch(void* const* d_in, const int* in_sizes, int n_in,
                              void* d_out, int out_size, void* d_ws, size_t ws_size,
                              hipStream_t stream) {
  const float* x        = (const float*)d_in[0];
  const float* sa_gamma = (const float*)d_in[1];
  const float* sa_wq    = (const float*)d_in[2];
  const float* sa_wkv   = (const float*)d_in[3];
  const float* sa_wo    = (const float*)d_in[4];
  const float* ta_gamma = (const float*)d_in[5];
  const float* ta_wq    = (const float*)d_in[6];
  const float* ta_wkv   = (const float*)d_in[7];
  const float* ta_wo    = (const float*)d_in[8];
  const float* sp_w1 = (const float*)d_in[9];
  const float* sp_b1 = (const float*)d_in[10];
  const float* sp_w2 = (const float*)d_in[11];
  const float* sp_b2 = (const float*)d_in[12];
  const float* sp_w3 = (const float*)d_in[13];
  const float* sp_b3 = (const float*)d_in[14];
  const float* tp_w1 = (const float*)d_in[15];
  const float* tp_b1 = (const float*)d_in[16];
  const float* tp_w2 = (const float*)d_in[17];
  const float* tp_b2 = (const float*)d_in[18];
  const float* tp_w3 = (const float*)d_in[19];
  const float* tp_b3 = (const float*)d_in[20];
  const float* ff_win   = (const float*)d_in[21];
  const float* ff_gamma = (const float*)d_in[22];
  const float* ff_wout  = (const float*)d_in[23];
  float* outp = (float*)d_out;

  char* ws = (char*)d_ws;
  size_t off = 0;
  auto alloc = [&](size_t bytes) -> char* {
    char* p = ws + off;
    off += (bytes + 255) & ~(size_t)255;
    return p;
  };
  const long T = 16384;  // tokens
  float*  xs = (float*)alloc((size_t)T * 512 * 4);
  bf16_t* xn = (bf16_t*)alloc((size_t)T * 512 * 2);
  bf16_t* qkv = (bf16_t*)alloc((size_t)T * 1536 * 2);
  bf16_t* vT = (bf16_t*)alloc(128ULL * 64 * 1024 * 2);
  bf16_t* ob = (bf16_t*)alloc((size_t)T * 512 * 2);
  bf16_t* wqkvT_sa = (bf16_t*)alloc(1536ULL * 512 * 2);
  bf16_t* woT_sa   = (bf16_t*)alloc(512ULL * 512 * 2);
  bf16_t* wqkvT_ta = (bf16_t*)alloc(1536ULL * 512 * 2);
  bf16_t* woT_ta   = (bf16_t*)alloc(512ULL * 512 * 2);
  bf16_t* winAT = (bf16_t*)alloc(1365ULL * 512 * 2);
  bf16_t* winGT = (bf16_t*)alloc(1365ULL * 512 * 2);
  bf16_t* woutT = (bf16_t*)alloc(512ULL * 1376 * 2);
  float* tab_sp = (float*)alloc(3969 * 8 * 4);
  float* tab_tp = (float*)alloc(15 * 8 * 4);

  char* big = ws + off;
  size_t remaining = (ws_size > off) ? (ws_size - off) : 0;
  const size_t S_PER_BF = 8ULL * 1024 * 1024 * 4;  // 8 heads x 1024 x 1024 fp32
  const size_t P_PER_BF = 8ULL * 1024 * 1024 * 2;  // bf16
  int CB = 1;
  {
    const int cand[5] = {16, 8, 4, 2, 1};
    for (int ci = 0; ci < 5; ++ci)
      if ((size_t)cand[ci] * (S_PER_BF + P_PER_BF) <= remaining) { CB = cand[ci]; break; }
  }
  float*  Sbuf = (float*)big;
  bf16_t* Pbuf = (bf16_t*)(big + (size_t)CB * S_PER_BF);
  float*  xt = (float*)big;           // reused after spatial chunks are done
  bf16_t* abuf = (bf16_t*)big;        // reused after temporal stage
  bf16_t* gbuf = abuf + (size_t)T * 1365;
  bf16_t* ynb = (bf16_t*)qkv;         // reuse qkv region (45.1MB <= 50.3MB)

  // 1) input layout: per b transpose (C=512 x FHW=8192) -> (8192 x 512)
  st_transpose2d<<<dim3(256, 16, 2), 256, 0, stream>>>(x, xs, 512, 8192,
                                                       (long long)512 * 8192, (long long)512 * 8192);
  // 2) weight transposes (fp32 KxN -> bf16 NxKpad)
  auto wt = [&](const float* src, bf16_t* dst, int K, int Kpad, int N, int srcld, int coloff) {
    long tot = (long)N * Kpad;
    st_wtrans<<<dim3((tot + 255) / 256), 256, 0, stream>>>(src, dst, K, Kpad, N, srcld, coloff, tot);
  };
  wt(sa_wq, wqkvT_sa, 512, 512, 512, 512, 0);
  wt(sa_wkv, wqkvT_sa + 512 * 512, 512, 512, 1024, 1024, 0);
  wt(sa_wo, woT_sa, 512, 512, 512, 512, 0);
  wt(ta_wq, wqkvT_ta, 512, 512, 512, 512, 0);
  wt(ta_wkv, wqkvT_ta + 512 * 512, 512, 512, 1024, 1024, 0);
  wt(ta_wo, woT_ta, 512, 512, 512, 512, 0);
  wt(ff_win, winAT, 512, 512, 1365, 2730, 0);
  wt(ff_win, winGT, 512, 512, 1365, 2730, 1365);
  wt(ff_wout, woutT, 1365, 1376, 512, 512, 0);
  // 3) CPB tables
  st_cpb<<<dim3(3969), 256, 0, stream>>>(sp_w1, sp_b1, sp_w2, sp_b2, sp_w3, sp_b3, tab_sp, 1);
  st_cpb<<<dim3(15), 256, 0, stream>>>(tp_w1, tp_b1, tp_w2, tp_b2, tp_w3, tp_b3, tab_tp, 0);

  // ---- spatial attention ----
  st_rmsnorm<<<dim3(4096), 256, 0, stream>>>(xs, sa_gamma, xn);
  st_gemm<true, false><<<dim3(128, 12, 1), 256, 0, stream>>>(
      xn, wqkvT_sa, (void*)qkv, nullptr, 16384, 1536, 512, 512, 512, 1536, 1, 0, 0, 0, 0, 0, 0);
  st_vtrans<<<dim3(32, 2, 128), 256, 0, stream>>>(qkv, vT);
  for (int bf0 = 0; bf0 < 16; bf0 += CB) {
    const bf16_t* qb = qkv + (size_t)bf0 * 1024 * 1536;
    st_gemm<false, false><<<dim3(8, 8, CB * 8), 256, 0, stream>>>(
        qb, qb + 512, (void*)Sbuf, nullptr, 1024, 1024, 64, 1536, 1536, 1024,
        8, 64LL, 1572864LL, 64LL, 1572864LL, 1048576LL, 8388608LL);
    st_softmax_sp<<<dim3(1024, CB * 8), 256, 0, stream>>>(Sbuf, Pbuf, tab_sp);
    st_gemm<true, false><<<dim3(8, 1, CB * 8), 256, 0, stream>>>(
        Pbuf, vT + (size_t)bf0 * 524288, (void*)(ob + (size_t)bf0 * 524288), nullptr,
        1024, 64, 1024, 1024, 1024, 512,
        8, 1048576LL, 8388608LL, 65536LL, 524288LL, 64LL, 524288LL);
  }
  st_gemm<false, true><<<dim3(128, 4, 1), 256, 0, stream>>>(
      ob, woT_sa, (void*)xs, xs, 16384, 512, 512, 512, 512, 512, 1, 0, 0, 0, 0, 0, 0);

  // ---- temporal attention ----
  st_permute<<<dim3(32768), 256, 0, stream>>>(xs, xt, 0);
  st_rmsnorm<<<dim3(4096), 256, 0, stream>>>(xt, ta_gamma, xn);
  st_gemm<true, false><<<dim3(128, 12, 1), 256, 0, stream>>>(
      xn, wqkvT_ta, (void*)qkv, nullptr, 16384, 1536, 512, 512, 512, 1536, 1, 0, 0, 0, 0, 0, 0);
  st_tattn<<<dim3(4096), 256, 0, stream>>>(qkv, tab_tp, ob);
  st_gemm<false, true><<<dim3(128, 4, 1), 256, 0, stream>>>(
      ob, woT_ta, (void*)xt, xt, 16384, 512, 512, 512, 512, 512, 1, 0, 0, 0, 0, 0, 0);
  st_permute<<<dim3(32768), 256, 0, stream>>>(xt, xs, 1);

  // ---- feed-forward ----
  st_cast<<<dim3(32768), 256, 0, stream>>>(xs, xn, T * 512);
  st_gemm<true, false><<<dim3(128, 11, 1), 256, 0, stream>>>(
      xn, winAT, (void*)abuf, nullptr, 16384, 1365, 512, 512, 512, 1365, 1, 0, 0, 0, 0, 0, 0);
  st_gemm<true, false><<<dim3(128, 11, 1), 256, 0, stream>>>(
      xn, winGT, (void*)gbuf, nullptr, 16384, 1365, 512, 512, 512, 1365, 1, 0, 0, 0, 0, 0, 0);
  st_glu<<<dim3(16384), 256, 0, stream>>>(abuf, gbuf, ff_gamma, ynb);
  st_gemm<false, true><<<dim3(128, 4, 1), 256, 0, stream>>>(
      ynb, woutT, (void*)xs, xs, 16384, 512, 1376, 1376, 1376, 512, 1, 0, 0, 0, 0, 0, 0);

  // ---- output layout: per b transpose (8192 x 512) -> (512 x 8192) ----
  st_transpose2d<<<dim3(16, 256, 2), 256, 0, stream>>>(xs, outp, 8192, 512,
                                                       (long long)8192 * 512, (long long)8192 * 512);
}

// Round 2
// 779.230 us; speedup vs baseline: 1.7482x; 1.7482x over previous
//
#include <hip/hip_runtime.h>
#include <cstdint>
#include <cstddef>

typedef __bf16 bf16_t;
typedef __bf16 bf16x8 __attribute__((ext_vector_type(8)));
typedef float floatx4 __attribute__((ext_vector_type(4)));

// ---------------- helpers ----------------
__device__ __forceinline__ float wred_sum(float v) {
#pragma unroll
  for (int off = 32; off > 0; off >>= 1) v += __shfl_xor(v, off);
  return v;
}
__device__ __forceinline__ void async16(const void* g, void* l) {
  __builtin_amdgcn_global_load_lds((const __attribute__((address_space(1))) void*)g,
                                   (__attribute__((address_space(3))) void*)l, 16, 0, 0);
}

// ---------------- generic batched bf16 GEMM (m97 structure) ----------------
template <bool OUT_BF16, bool RESID>
__global__ __launch_bounds__(256) void st_gemm(
    const bf16_t* __restrict__ A, const bf16_t* __restrict__ B, void* Cp,
    const float* Res, int M, int N, int K, int lda, int ldb, int ldc, int nb1,
    long long sa1, long long sa2, long long sb1, long long sb2,
    long long sc1, long long sc2) {
  __shared__ bf16_t sA[128 * 32];
  __shared__ bf16_t sB[128 * 32];
  const int z = blockIdx.z;
  const int z1 = z % nb1, z2 = z / nb1;
  A += z1 * sa1 + z2 * sa2;
  B += z1 * sb1 + z2 * sb2;
  const long long coff = z1 * sc1 + z2 * sc2;
  const int tid = threadIdx.x;
  const int bm = blockIdx.x, bn = blockIdx.y;
  const int lane = tid & 63;
  const int wave = tid >> 6;
  const int wm = (wave >> 1) * 64, wn = (wave & 1) * 64;
  const int rowf = lane & 15, kq = (lane >> 4) * 8;

  floatx4 acc[4][4];
#pragma unroll
  for (int i = 0; i < 4; ++i)
#pragma unroll
    for (int j = 0; j < 4; ++j) acc[i][j] = floatx4{0.f, 0.f, 0.f, 0.f};

  for (int kt = 0; kt < K; kt += 32) {
#pragma unroll
    for (int it = 0; it < 2; ++it) {
      int slot = it * 256 + tid;
      int mi = slot >> 2, kc = slot & 3;
      int ar = bm * 128 + mi; if (ar > M - 1) ar = M - 1;
      int br = bn * 128 + mi; if (br > N - 1) br = N - 1;
      async16(A + (size_t)ar * lda + kt + kc * 8, (char*)sA + slot * 16);
      async16(B + (size_t)br * ldb + kt + kc * 8, (char*)sB + slot * 16);
    }
    __syncthreads();
    bf16x8 af[4], bv[4];
#pragma unroll
    for (int i = 0; i < 4; ++i) {
      af[i] = *(const bf16x8*)(sA + (wm + i * 16 + rowf) * 32 + kq);
      bv[i] = *(const bf16x8*)(sB + (wn + i * 16 + rowf) * 32 + kq);
    }
#pragma unroll
    for (int i = 0; i < 4; ++i)
#pragma unroll
      for (int j = 0; j < 4; ++j)
        acc[i][j] = __builtin_amdgcn_mfma_f32_16x16x32_bf16(af[i], bv[j], acc[i][j], 0, 0, 0);
    __syncthreads();
  }

  const int colBase = bn * 128 + wn + (lane & 15);
  const int rowBase = bm * 128 + wm + (lane >> 4) * 4;
#pragma unroll
  for (int i = 0; i < 4; ++i) {
#pragma unroll
    for (int j = 0; j < 4; ++j) {
      int col = colBase + j * 16;
      if (col >= N) continue;
#pragma unroll
      for (int r = 0; r < 4; ++r) {
        int row = rowBase + i * 16 + r;
        if (row >= M) continue;
        long long idx = coff + (long long)row * ldc + col;
        float v = acc[i][j][r];
        if (RESID) v += Res[idx];
        if (OUT_BF16) ((bf16_t*)Cp)[idx] = (bf16_t)v;
        else          ((float*)Cp)[idx] = v;
      }
    }
  }
}

// ---------------- tiled fp32 transpose (R x C) -> (C x R), batched ----------------
__global__ __launch_bounds__(256) void st_transpose2d(
    const float* __restrict__ in, float* __restrict__ out, int R, int Cc,
    long long inb, long long outb) {
  __shared__ float tile[32][33];
  const int ct = blockIdx.x, rt = blockIdx.y, b = blockIdx.z;
  in += (long long)b * inb;
  out += (long long)b * outb;
  const int tx = threadIdx.x & 31, ty = threadIdx.x >> 5;
#pragma unroll
  for (int k = 0; k < 4; ++k) {
    int r = rt * 32 + ty + k * 8;
    int c = ct * 32 + tx;
    tile[ty + k * 8][tx] = in[(size_t)r * Cc + c];
  }
  __syncthreads();
#pragma unroll
  for (int k = 0; k < 4; ++k) {
    int c = ct * 32 + ty + k * 8;
    int r = rt * 32 + tx;
    out[(size_t)c * R + r] = tile[tx][ty + k * 8];
  }
}

// ---------------- weight transpose fp32 (K x N) -> bf16 (N x Kpad) ----------------
__global__ void st_wtrans(const float* __restrict__ src, bf16_t* __restrict__ dst,
                          int K, int Kpad, int N, int srcld, int coloff, long total) {
  long idx = (long)blockIdx.x * 256 + threadIdx.x;
  if (idx >= total) return;
  int kp = (int)(idx % Kpad);
  int n = (int)(idx / Kpad);
  float v = (kp < K) ? src[(size_t)kp * srcld + coloff + n] : 0.f;
  dst[idx] = (bf16_t)v;
}

// ---------------- CPB MLP tables ----------------
// 2d: tab2d[o*4000 + pos] (bf16, head-major);  1d: tab1d[o*15 + pos] (f32)
__global__ __launch_bounds__(256) void st_cpb(
    const float* __restrict__ w1, const float* __restrict__ b1,
    const float* __restrict__ w2, const float* __restrict__ b2,
    const float* __restrict__ w3, const float* __restrict__ b3,
    bf16_t* __restrict__ tab2d, float* __restrict__ tab1d, int two_d) {
  const int pos = blockIdx.x, t = threadIdx.x;
  float r0, r1 = 0.f;
  if (two_d) { r0 = (float)(pos / 63 - 31); r1 = (float)(pos % 63 - 31); }
  else { r0 = (float)(pos - 7); }
  __shared__ float sh[256];
  float h = r0 * w1[t] + (two_d ? r1 * w1[256 + t] : 0.f) + b1[t];
  h = h / (1.f + expf(-h));
  sh[t] = h;
  __syncthreads();
  float h2 = b2[t];
  for (int j = 0; j < 256; ++j) h2 += sh[j] * w2[j * 256 + t];
  h2 = h2 / (1.f + expf(-h2));
  __syncthreads();
  sh[t] = h2;
  __syncthreads();
  if (t < 8) {
    float o = b3[t];
    for (int j = 0; j < 256; ++j) o += sh[j] * w3[j * 8 + t];
    if (two_d) tab2d[t * 4000 + pos] = (bf16_t)o;
    else tab1d[t * 15 + pos] = o;
  }
}

// ---------------- RMS norm -> bf16 ----------------
__global__ __launch_bounds__(256) void st_rmsnorm(const float* __restrict__ x,
                                                  const float* __restrict__ gamma,
                                                  bf16_t* __restrict__ y) {
  const int token = blockIdx.x * 4 + (threadIdx.x >> 6);
  const int lane = threadIdx.x & 63;
  const float* xr = x + (size_t)token * 512;
  float v[8];
  float ss = 0.f;
#pragma unroll
  for (int k = 0; k < 8; ++k) { v[k] = xr[k * 64 + lane]; ss += v[k] * v[k]; }
  ss = wred_sum(ss);
  const float r = 22.627416998f / fmaxf(sqrtf(ss), 1e-12f);
  bf16_t* yr = y + (size_t)token * 512;
#pragma unroll
  for (int k = 0; k < 8; ++k) yr[k * 64 + lane] = (bf16_t)(v[k] * r * gamma[k * 64 + lane]);
}

__global__ void st_cast(const float* __restrict__ in, bf16_t* __restrict__ out, long n) {
  long i = (long)blockIdx.x * 256 + threadIdx.x;
  if (i < n) out[i] = (bf16_t)in[i];
}

// ---------------- V transpose: qkv -> vT[(bf*8+h)][d][j] ----------------
__global__ __launch_bounds__(256) void st_vtrans(const bf16_t* __restrict__ qkv,
                                                 bf16_t* __restrict__ vT) {
  __shared__ float tile[32][33];
  const int jt = blockIdx.x, dt = blockIdx.y, z = blockIdx.z;
  const int bf = z >> 3, h = z & 7;
  const int tx = threadIdx.x & 31, ty = threadIdx.x >> 5;
#pragma unroll
  for (int k = 0; k < 4; ++k) {
    int j = jt * 32 + ty + k * 8;
    int d = dt * 32 + tx;
    tile[ty + k * 8][tx] = (float)qkv[((size_t)(bf * 1024 + j)) * 1536 + 1024 + h * 64 + d];
  }
  __syncthreads();
#pragma unroll
  for (int k = 0; k < 4; ++k) {
    int d = dt * 32 + ty + k * 8;
    int j = jt * 32 + tx;
    vT[((size_t)z * 64 + d) * 1024 + j] = (bf16_t)tile[tx][ty + k * 8];
  }
}

// ---------------- fused flash spatial attention ----------------
// grid (qtile=8, z=bf*8+h=128). Block: 256 thr = 4 waves; wave owns rows
// [wave*32, +32) of the 128-row Q tile. K-tiles of 64 cols, no max-sub
// (scores bounded; fp32 exp safe). Bias: tab idx = f(i)-f(j)+1984,
// f(p)=(p>>5)*63+(p&31). XOR swizzle on k-chunks kills the 16-way LDS
// bank conflict from 128B row strides.
__global__ __launch_bounds__(256) void st_flash(
    const bf16_t* __restrict__ qkv, const bf16_t* __restrict__ vT,
    const bf16_t* __restrict__ tabb, bf16_t* __restrict__ ob) {
  __shared__ bf16_t ldsQ[128 * 64];
  __shared__ bf16_t ldsK[64 * 64];
  __shared__ bf16_t ldsV[64 * 64];
  __shared__ bf16_t ldsP[4 * 32 * 72];
  __shared__ bf16_t ldsT[4000];
  const int qtile = blockIdx.x;
  const int z = blockIdx.y;
  const int bf = z >> 3, h = z & 7;
  const int tid = threadIdx.x;
  const int lane = tid & 63, wave = tid >> 6;
  const int cl = lane & 15, g = lane >> 4;
  const size_t qkvBase = (size_t)bf * 1024 * 1536 + h * 64;
  // stage Q (swizzled) + bias table
#pragma unroll
  for (int it = 0; it < 4; ++it) {
    int slot = it * 256 + tid;
    int row = slot >> 3, c = slot & 7;
    int cs = c ^ (row & 7);
    async16(qkv + qkvBase + (size_t)(qtile * 128 + row) * 1536 + cs * 8,
            (char*)ldsQ + slot * 16);
  }
#pragma unroll
  for (int it = 0; it < 2; ++it) {
    int slot = it * 256 + tid;
    if (slot < 500)
      async16(tabb + h * 4000 + slot * 8, (char*)ldsT + slot * 16);
  }
  int fi[2][4];
#pragma unroll
  for (int it = 0; it < 2; ++it)
#pragma unroll
    for (int r = 0; r < 4; ++r) {
      int i = qtile * 128 + wave * 32 + it * 16 + g * 4 + r;
      fi[it][r] = (i >> 5) * 63 + (i & 31) + 1984;
    }
  float lsum[2][4];
  floatx4 oacc[2][4];
#pragma unroll
  for (int it = 0; it < 2; ++it)
#pragma unroll
    for (int r = 0; r < 4; ++r) lsum[it][r] = 0.f;
#pragma unroll
  for (int it = 0; it < 2; ++it)
#pragma unroll
    for (int dt = 0; dt < 4; ++dt) oacc[it][dt] = floatx4{0.f, 0.f, 0.f, 0.f};

  bf16_t* ldsPw = ldsP + wave * (32 * 72);
  const size_t vBase = (size_t)z * 64 * 1024;

  for (int j0 = 0; j0 < 1024; j0 += 64) {
    // stage K, V^T tiles (swizzled)
#pragma unroll
    for (int it = 0; it < 2; ++it) {
      int slot = it * 256 + tid;
      int row = slot >> 3, c = slot & 7;
      int cs = c ^ (row & 7);
      async16(qkv + qkvBase + 512 + (size_t)(j0 + row) * 1536 + cs * 8,
              (char*)ldsK + slot * 16);
      async16(vT + vBase + (size_t)row * 1024 + j0 + cs * 8,
              (char*)ldsV + slot * 16);
    }
    __syncthreads();
    // S = Q K^T
    floatx4 sacc[2][4];
#pragma unroll
    for (int it = 0; it < 2; ++it)
#pragma unroll
      for (int jt = 0; jt < 4; ++jt) sacc[it][jt] = floatx4{0.f, 0.f, 0.f, 0.f};
#pragma unroll
    for (int ks = 0; ks < 2; ++ks) {
      bf16x8 aq[2];
#pragma unroll
      for (int it = 0; it < 2; ++it) {
        int row = wave * 32 + it * 16 + cl;
        int cs = (g + ks * 4) ^ (row & 7);
        aq[it] = *(const bf16x8*)(ldsQ + row * 64 + cs * 8);
      }
#pragma unroll
      for (int jt = 0; jt < 4; ++jt) {
        int col = jt * 16 + cl;
        int cs = (g + ks * 4) ^ (col & 7);
        bf16x8 bk = *(const bf16x8*)(ldsK + col * 64 + cs * 8);
#pragma unroll
        for (int it = 0; it < 2; ++it)
          sacc[it][jt] = __builtin_amdgcn_mfma_f32_16x16x32_bf16(aq[it], bk, sacc[it][jt], 0, 0, 0);
      }
    }
    // bias + exp + row-sum accumulate, P -> wave-private LDS
#pragma unroll
    for (int jt = 0; jt < 4; ++jt) {
      int j = j0 + jt * 16 + cl;
      int fj = (j >> 5) * 63 + (j & 31);
#pragma unroll
      for (int it = 0; it < 2; ++it) {
#pragma unroll
        for (int r = 0; r < 4; ++r) {
          float e = __expf(sacc[it][jt][r] * 0.125f + (float)ldsT[fi[it][r] - fj]);
          lsum[it][r] += e;
          ldsPw[(it * 16 + g * 4 + r) * 72 + jt * 16 + cl] = (bf16_t)e;
        }
      }
    }
    // O += P V  (wave-private P; compiler orders ds_write->ds_read via lgkmcnt)
#pragma unroll
    for (int ks = 0; ks < 2; ++ks) {
      bf16x8 ap[2];
#pragma unroll
      for (int it = 0; it < 2; ++it)
        ap[it] = *(const bf16x8*)(ldsPw + (it * 16 + cl) * 72 + (g + ks * 4) * 8);
#pragma unroll
      for (int dt = 0; dt < 4; ++dt) {
        int d = dt * 16 + cl;
        int cs = (g + ks * 4) ^ (d & 7);
        bf16x8 bv = *(const bf16x8*)(ldsV + d * 64 + cs * 8);
#pragma unroll
        for (int it = 0; it < 2; ++it)
          oacc[it][dt] = __builtin_amdgcn_mfma_f32_16x16x32_bf16(ap[it], bv, oacc[it][dt], 0, 0, 0);
      }
    }
    __syncthreads();
  }
  // normalize + write
#pragma unroll
  for (int it = 0; it < 2; ++it)
#pragma unroll
    for (int r = 0; r < 4; ++r) {
#pragma unroll
      for (int x = 1; x < 16; x <<= 1) lsum[it][r] += __shfl_xor(lsum[it][r], x);
      lsum[it][r] = 1.f / lsum[it][r];
    }
#pragma unroll
  for (int it = 0; it < 2; ++it) {
#pragma unroll
    for (int r = 0; r < 4; ++r) {
      int i = qtile * 128 + wave * 32 + it * 16 + g * 4 + r;
      size_t base = ((size_t)bf * 1024 + i) * 512 + h * 64;
#pragma unroll
      for (int dt = 0; dt < 4; ++dt)
        ob[base + dt * 16 + cl] = (bf16_t)(oacc[it][dt][r] * lsum[it][r]);
    }
  }
}

// ---------------- temporal attention (seq=8), log-transpose reduce ----------------
__global__ __launch_bounds__(256) void st_tattn2(const bf16_t* __restrict__ qkv,
                                                 const float* __restrict__ tabf,
                                                 bf16_t* __restrict__ o) {
  const int wg = blockIdx.x * 4 + (threadIdx.x >> 6);
  const int bhw = wg >> 3, head = wg & 7;
  const int lane = threadIdx.x & 63;
  const size_t base = (size_t)bhw * 8 * 1536 + head * 64 + lane;
  float q[8], k[8], v[8];
#pragma unroll
  for (int f = 0; f < 8; ++f) {
    q[f] = (float)qkv[base + (size_t)f * 1536];
    k[f] = (float)qkv[base + (size_t)f * 1536 + 512];
    v[f] = (float)qkv[base + (size_t)f * 1536 + 1024];
  }
  float p[64];
#pragma unroll
  for (int i = 0; i < 8; ++i)
#pragma unroll
    for (int j = 0; j < 8; ++j) p[i * 8 + j] = q[i] * k[j];
  // log-transpose reduce: after this, lane L holds full d-sum for pair L=(i*8+j)
#pragma unroll
  for (int st = 32; st >= 1; st >>= 1) {
    const bool hi = (lane & st) != 0;
#pragma unroll
    for (int m = 0; m < st; ++m) {
      float give = hi ? p[m] : p[m + st];
      float keep = hi ? p[m + st] : p[m];
      p[m] = keep + __shfl_xor(give, st);
    }
  }
  const int i = lane >> 3, j = lane & 7;
  float e = __expf(p[0] * 0.125f + tabf[head * 15 + i - j + 7]);
  float sm = e;
  sm += __shfl_xor(sm, 1);
  sm += __shfl_xor(sm, 2);
  sm += __shfl_xor(sm, 4);
  const float prob = e / sm;
  float acc[8];
#pragma unroll
  for (int ii = 0; ii < 8; ++ii) acc[ii] = 0.f;
#pragma unroll
  for (int ii = 0; ii < 8; ++ii)
#pragma unroll
    for (int jj = 0; jj < 8; ++jj)
      acc[ii] += __shfl(prob, ii * 8 + jj) * v[jj];
#pragma unroll
  for (int ii = 0; ii < 8; ++ii)
    o[(size_t)(bhw * 8 + ii) * 512 + head * 64 + lane] = (bf16_t)acc[ii];
}

// ---------------- permute (b,f,hw,c) <-> (b,hw,f,c) ----------------
__global__ void st_permute(const float* __restrict__ in, float* __restrict__ out, int dir) {
  size_t idx = (size_t)blockIdx.x * 256 + threadIdx.x;
  int c = (int)(idx & 511);
  size_t r = idx >> 9;
  size_t src;
  if (dir == 0) {
    int f = (int)(r & 7);
    int hw = (int)((r >> 3) & 1023);
    int b = (int)(r >> 13);
    src = ((((size_t)b * 8 + f) * 1024 + hw) << 9) + c;
  } else {
    int hw = (int)(r & 1023);
    int f = (int)((r >> 10) & 7);
    int b = (int)(r >> 13);
    src = ((((size_t)b * 1024 + hw) * 8 + f) << 9) + c;
  }
  out[idx] = in[src];
}

// ---------------- GeGLU + temporal shift + RMS -> yn bf16 (K padded to 1376) ----------------
__global__ __launch_bounds__(256) void st_glu(const bf16_t* __restrict__ a,
                                              const bf16_t* __restrict__ g,
                                              const float* __restrict__ gamma,
                                              bf16_t* __restrict__ yn) {
  const int t = blockIdx.x;
  const int tid = threadIdx.x;
  const int f = (t >> 10) & 7;
  float y[6];
  float ss = 0.f;
#pragma unroll
  for (int kk = 0; kk < 6; ++kk) {
    int c = kk * 256 + tid;
    float yv = 0.f;
    if (c < 1365) {
      long src = t;
      bool valid = true;
      if (c >= 683) { if (f == 0) valid = false; else src = t - 1024; }
      if (valid) {
        float av = (float)a[src * 1365 + c];
        float gv = (float)g[src * 1365 + c];
        yv = av * 0.5f * gv * (1.f + erff(gv * 0.70710678f));
      }
    }
    y[kk] = yv;
    ss += yv * yv;
  }
  __shared__ float red[4];
  ss = wred_sum(ss);
  if ((tid & 63) == 0) red[tid >> 6] = ss;
  __syncthreads();
  ss = red[0] + red[1] + red[2] + red[3];
  const float r = sqrtf(1365.f) / fmaxf(sqrtf(ss), 1e-12f);
#pragma unroll
  for (int kk = 0; kk < 6; ++kk) {
    int c = kk * 256 + tid;
    if (c < 1365) yn[(size_t)t * 1376 + c] = (bf16_t)(y[kk] * r * gamma[c]);
  }
  if (tid < 11) yn[(size_t)t * 1376 + 1365 + tid] = (bf16_t)0.f;
}

// ---------------- launcher ----------------
extern "C" void kernel_launch(void* const* d_in, const int* in_sizes, int n_in,
                              void* d_out, int out_size, void* d_ws, size_t ws_size,
                              hipStream_t stream) {
  const float* x        = (const float*)d_in[0];
  const float* sa_gamma = (const float*)d_in[1];
  const float* sa_wq    = (const float*)d_in[2];
  const float* sa_wkv   = (const float*)d_in[3];
  const float* sa_wo    = (const float*)d_in[4];
  const float* ta_gamma = (const float*)d_in[5];
  const float* ta_wq    = (const float*)d_in[6];
  const float* ta_wkv   = (const float*)d_in[7];
  const float* ta_wo    = (const float*)d_in[8];
  const float* sp_w1 = (const float*)d_in[9];
  const float* sp_b1 = (const float*)d_in[10];
  const float* sp_w2 = (const float*)d_in[11];
  const float* sp_b2 = (const float*)d_in[12];
  const float* sp_w3 = (const float*)d_in[13];
  const float* sp_b3 = (const float*)d_in[14];
  const float* tp_w1 = (const float*)d_in[15];
  const float* tp_b1 = (const float*)d_in[16];
  const float* tp_w2 = (const float*)d_in[17];
  const float* tp_b2 = (const float*)d_in[18];
  const float* tp_w3 = (const float*)d_in[19];
  const float* tp_b3 = (const float*)d_in[20];
  const float* ff_win   = (const float*)d_in[21];
  const float* ff_gamma = (const float*)d_in[22];
  const float* ff_wout  = (const float*)d_in[23];
  float* outp = (float*)d_out;

  char* ws = (char*)d_ws;
  size_t off = 0;
  auto alloc = [&](size_t bytes) -> char* {
    char* p = ws + off;
    off += (bytes + 255) & ~(size_t)255;
    return p;
  };
  const long T = 16384;
  // region plan (stage-overlapped; ~205 MB total):
  float*  xs  = (float*)alloc((size_t)T * 512 * 4);    // residual stream
  bf16_t* xn  = (bf16_t*)alloc((size_t)T * 512 * 2);   // normed input
  char*   R2  = alloc((size_t)T * 1536 * 2);           // qkv | FF: abuf
  char*   R3  = alloc((size_t)T * 1536 * 2);           // vT+ob | xt+ob | gbuf
  bf16_t* ynb = (bf16_t*)alloc((size_t)T * 1376 * 2);
  bf16_t* wqkvT_sa = (bf16_t*)alloc(1536ULL * 512 * 2);
  bf16_t* woT_sa   = (bf16_t*)alloc(512ULL * 512 * 2);
  bf16_t* wqkvT_ta = (bf16_t*)alloc(1536ULL * 512 * 2);
  bf16_t* woT_ta   = (bf16_t*)alloc(512ULL * 512 * 2);
  bf16_t* winAT = (bf16_t*)alloc(1365ULL * 512 * 2);
  bf16_t* winGT = (bf16_t*)alloc(1365ULL * 512 * 2);
  bf16_t* woutT = (bf16_t*)alloc(512ULL * 1376 * 2);
  bf16_t* tabb  = (bf16_t*)alloc(8 * 4000 * 2);
  float*  tabf  = (float*)alloc(8 * 15 * 4);

  bf16_t* qkv  = (bf16_t*)R2;
  bf16_t* abuf = (bf16_t*)R2;                       // FF (qkv dead)
  bf16_t* vT   = (bf16_t*)R3;                       // spatial
  bf16_t* ob_s = (bf16_t*)(R3 + (size_t)T * 512 * 2);
  float*  xt   = (float*)R3;                        // temporal
  bf16_t* ob_t = (bf16_t*)(R3 + (size_t)T * 512 * 4);
  bf16_t* gbuf = (bf16_t*)R3;                       // FF

  // 1) input: per b transpose (512 x 8192) -> (8192 x 512)
  st_transpose2d<<<dim3(256, 16, 2), 256, 0, stream>>>(x, xs, 512, 8192,
                                                       (long long)512 * 8192, (long long)512 * 8192);
  // 2) weight transposes
  auto wt = [&](const float* src, bf16_t* dst, int K, int Kpad, int N, int srcld, int coloff) {
    long tot = (long)N * Kpad;
    st_wtrans<<<dim3((tot + 255) / 256), 256, 0, stream>>>(src, dst, K, Kpad, N, srcld, coloff, tot);
  };
  wt(sa_wq, wqkvT_sa, 512, 512, 512, 512, 0);
  wt(sa_wkv, wqkvT_sa + 512 * 512, 512, 512, 1024, 1024, 0);
  wt(sa_wo, woT_sa, 512, 512, 512, 512, 0);
  wt(ta_wq, wqkvT_ta, 512, 512, 512, 512, 0);
  wt(ta_wkv, wqkvT_ta + 512 * 512, 512, 512, 1024, 1024, 0);
  wt(ta_wo, woT_ta, 512, 512, 512, 512, 0);
  wt(ff_win, winAT, 512, 512, 1365, 2730, 0);
  wt(ff_win, winGT, 512, 512, 1365, 2730, 1365);
  wt(ff_wout, woutT, 1365, 1376, 512, 512, 0);
  // 3) CPB tables
  st_cpb<<<dim3(3969), 256, 0, stream>>>(sp_w1, sp_b1, sp_w2, sp_b2, sp_w3, sp_b3, tabb, tabf, 1);
  st_cpb<<<dim3(15), 256, 0, stream>>>(tp_w1, tp_b1, tp_w2, tp_b2, tp_w3, tp_b3, tabb, tabf, 0);

  // ---- spatial attention ----
  st_rmsnorm<<<dim3(4096), 256, 0, stream>>>(xs, sa_gamma, xn);
  st_gemm<true, false><<<dim3(128, 12, 1), 256, 0, stream>>>(
      xn, wqkvT_sa, (void*)qkv, nullptr, 16384, 1536, 512, 512, 512, 1536, 1, 0, 0, 0, 0, 0, 0);
  st_vtrans<<<dim3(32, 2, 128), 256, 0, stream>>>(qkv, vT);
  st_flash<<<dim3(8, 128), 256, 0, stream>>>(qkv, vT, tabb, ob_s);
  st_gemm<false, true><<<dim3(128, 4, 1), 256, 0, stream>>>(
      ob_s, woT_sa, (void*)xs, xs, 16384, 512, 512, 512, 512, 512, 1, 0, 0, 0, 0, 0, 0);

  // ---- temporal attention ----
  st_permute<<<dim3(32768), 256, 0, stream>>>(xs, xt, 0);
  st_rmsnorm<<<dim3(4096), 256, 0, stream>>>(xt, ta_gamma, xn);
  st_gemm<true, false><<<dim3(128, 12, 1), 256, 0, stream>>>(
      xn, wqkvT_ta, (void*)qkv, nullptr, 16384, 1536, 512, 512, 512, 1536, 1, 0, 0, 0, 0, 0, 0);
  st_tattn2<<<dim3(4096), 256, 0, stream>>>(qkv, tabf, ob_t);
  st_gemm<false, true><<<dim3(128, 4, 1), 256, 0, stream>>>(
      ob_t, woT_ta, (void*)xt, xt, 16384, 512, 512, 512, 512, 512, 1, 0, 0, 0, 0, 0, 0);
  st_permute<<<dim3(32768), 256, 0, stream>>>(xt, xs, 1);

  // ---- feed-forward ----
  st_cast<<<dim3(32768), 256, 0, stream>>>(xs, xn, T * 512);
  st_gemm<true, false><<<dim3(128, 11, 1), 256, 0, stream>>>(
      xn, winAT, (void*)abuf, nullptr, 16384, 1365, 512, 512, 512, 1365, 1, 0, 0, 0, 0, 0, 0);
  st_gemm<true, false><<<dim3(128, 11, 1), 256, 0, stream>>>(
      xn, winGT, (void*)gbuf, nullptr, 16384, 1365, 512, 512, 512, 1365, 1, 0, 0, 0, 0, 0, 0);
  st_glu<<<dim3(16384), 256, 0, stream>>>(abuf, gbuf, ff_gamma, ynb);
  st_gemm<false, true><<<dim3(128, 4, 1), 256, 0, stream>>>(
      ynb, woutT, (void*)xs, xs, 16384, 512, 1376, 1376, 1376, 512, 1, 0, 0, 0, 0, 0, 0);

  // ---- output: per b transpose (8192 x 512) -> (512 x 8192) ----
  st_transpose2d<<<dim3(16, 256, 2), 256, 0, stream>>>(xs, outp, 8192, 512,
                                                       (long long)8192 * 512, (long long)8192 * 512);
}